// Round 1
// baseline (1902.984 us; speedup 1.0000x reference)
//
#include <hip/hip_runtime.h>
#include <hip/hip_bf16.h>

typedef _Float16 half8  __attribute__((ext_vector_type(8)));
typedef _Float16 half4_t __attribute__((ext_vector_type(4)));
typedef float    floatx4 __attribute__((ext_vector_type(4)));
typedef int      intx4   __attribute__((ext_vector_type(4)));

#define B_DIM   16384
#define IN_D    2048
#define HV_D    8192
#define NC      1000
#define NCP     1024
#define SCORES_N (B_DIM * NC)

// async global->LDS, 16B per lane; LDS side is wave-uniform base + lane*16
#define GLD16(gp, lp) __builtin_amdgcn_global_load_lds( \
    (const __attribute__((address_space(1))) void*)(gp), \
    (__attribute__((address_space(3))) void*)(lp), 16, 0, 0)

// ---------- P1: Dekker split x (fp32) -> x_hi + x_lo (fp16), exact vs fp32 ----------
__global__ void k_split(const float* __restrict__ x, _Float16* __restrict__ xh,
                        _Float16* __restrict__ xl) {
    size_t i = (size_t)blockIdx.x * 256 + threadIdx.x;   // one float4 per thread
    floatx4 v = ((const floatx4*)x)[i];
    half4_t h, l;
#pragma unroll
    for (int j = 0; j < 4; ++j) {
        _Float16 hh = (_Float16)v[j];
        h[j] = hh;
        l[j] = (_Float16)(v[j] - (float)hh);   // v-hh exact in fp32 (Sterbenz)
    }
    ((half4_t*)xh)[i] = h;
    ((half4_t*)xl)[i] = l;
}

// ---------- P2: proj [K=2048][N=8192] fp32 -> projT [N][K] fp16 (LDS-tiled) ----------
__global__ void k_transpose_proj(const float* __restrict__ p, _Float16* __restrict__ pT) {
    __shared__ float tile[64][65];
    const int t = threadIdx.x;
    const int nt = blockIdx.x * 64;   // n tile
    const int kt = blockIdx.y * 64;   // k tile
    const int tr = t >> 4, tc = (t & 15) * 4;
#pragma unroll
    for (int s = 0; s < 4; ++s) {
        int r = tr + s * 16;
        floatx4 v = *(const floatx4*)&p[(size_t)(kt + r) * HV_D + nt + tc];
        tile[r][tc] = v[0]; tile[r][tc + 1] = v[1];
        tile[r][tc + 2] = v[2]; tile[r][tc + 3] = v[3];
    }
    __syncthreads();
#pragma unroll
    for (int s = 0; s < 4; ++s) {
        int rn = tr + s * 16;
        half4_t o;
#pragma unroll
        for (int j = 0; j < 4; ++j) o[j] = (_Float16)tile[tc + j][rn];
        *(half4_t*)&pT[(size_t)(nt + rn) * IN_D + kt + tc] = o;
    }
}

// ---------- P3: class_hv [K=8192][1000] fp32 -> classT [1024][8192] i8, zero-padded ----------
__global__ void k_pack_class(const float* __restrict__ c, signed char* __restrict__ cT) {
    int tid = blockIdx.x * 256 + threadIdx.x;   // 2,097,152 threads, 4 k each
    int idx = tid * 4;
    int n = idx >> 13;
    int k = idx & (HV_D - 1);
    int w = 0;
    if (n < NC) {
#pragma unroll
        for (int j = 0; j < 4; ++j) {
            float v = c[(size_t)(k + j) * NC + n];
            int b = (v >= 0.f) ? 1 : -1;
            w |= (b & 0xff) << (8 * j);
        }
    }
    *(int*)&cT[(size_t)n * HV_D + k] = w;
}

// ---------- G1: hv = x@proj via fp16 hi/lo split, binarize, write fp32 + i8 ----------
// 128x128 tile, BK=64, 4 waves (2x2), each wave 64x64 as 4x4 of 16x16x32 f16 MFMA.
__launch_bounds__(256, 2)
__global__ void k_gemm1(const _Float16* __restrict__ xh, const _Float16* __restrict__ xl,
                        const _Float16* __restrict__ pT,
                        float* __restrict__ hv_out, signed char* __restrict__ hvb) {
    __shared__ _Float16 sAh[128 * 64];
    __shared__ _Float16 sAl[128 * 64];
    __shared__ _Float16 sB [128 * 64];
    const int t = threadIdx.x;
    const int w = t >> 6, l = t & 63;
    const int m0 = blockIdx.y * 128, n0 = blockIdx.x * 128;
    const int wm = (w >> 1) * 64, wn = (w & 1) * 64;
    const int lm = l & 15, kq = l >> 4;
    // staging: lane slice of [128][64] f16 tile, wave-contiguous LDS order
    const int srow  = w * 32 + (l >> 3);      // + i*8
    const int scol  = (l & 7) * 8;
    const int sbyte = w * 4096 + l * 16;      // + i*1024

    floatx4 acc[4][4] = {};

    for (int k0 = 0; k0 < IN_D; k0 += 64) {
        __syncthreads();
#pragma unroll
        for (int i = 0; i < 4; ++i) {
            const int r = srow + i * 8;
            const size_t ga = (size_t)(m0 + r) * IN_D + k0 + scol;
            const size_t gb = (size_t)(n0 + r) * IN_D + k0 + scol;
            const int lo = sbyte + i * 1024;
            GLD16(xh + ga, (char*)sAh + lo);
            GLD16(xl + ga, (char*)sAl + lo);
            GLD16(pT + gb, (char*)sB  + lo);
        }
        __syncthreads();
#pragma unroll
        for (int ks = 0; ks < 2; ++ks) {
            half8 b[4];
#pragma unroll
            for (int ns = 0; ns < 4; ++ns)
                b[ns] = *(const half8*)&sB[(wn + ns * 16 + lm) * 64 + ks * 32 + kq * 8];
#pragma unroll
            for (int ms = 0; ms < 4; ++ms) {
                half8 a = *(const half8*)&sAh[(wm + ms * 16 + lm) * 64 + ks * 32 + kq * 8];
#pragma unroll
                for (int ns = 0; ns < 4; ++ns)
                    acc[ms][ns] = __builtin_amdgcn_mfma_f32_16x16x32_f16(a, b[ns], acc[ms][ns], 0, 0, 0);
            }
#pragma unroll
            for (int ms = 0; ms < 4; ++ms) {
                half8 a = *(const half8*)&sAl[(wm + ms * 16 + lm) * 64 + ks * 32 + kq * 8];
#pragma unroll
                for (int ns = 0; ns < 4; ++ns)
                    acc[ms][ns] = __builtin_amdgcn_mfma_f32_16x16x32_f16(a, b[ns], acc[ms][ns], 0, 0, 0);
            }
        }
    }

    // epilogue: C/D layout col=lane&15, row=(lane>>4)*4+reg
#pragma unroll
    for (int ms = 0; ms < 4; ++ms) {
#pragma unroll
        for (int ns = 0; ns < 4; ++ns) {
            const int m = m0 + wm + ms * 16 + kq * 4;
            const int n = n0 + wn + ns * 16 + lm;
#pragma unroll
            for (int r = 0; r < 4; ++r) {
                const int pos = (acc[ms][ns][r] >= 0.f);
                const size_t o = (size_t)(m + r) * HV_D + n;
                hv_out[o] = pos ? 1.f : -1.f;
                hvb[o] = (signed char)(pos ? 1 : -1);
            }
        }
    }
}

// ---------- G2: scores = hv_bin @ class_hv, exact in i8 (K=8192) ----------
__launch_bounds__(256, 2)
__global__ void k_gemm2(const signed char* __restrict__ hvb, const signed char* __restrict__ cT,
                        float* __restrict__ scores) {
    __shared__ signed char sA[128 * 64];
    __shared__ signed char sB[128 * 64];
    const int t = threadIdx.x;
    const int w = t >> 6, l = t & 63;
    const int m0 = blockIdx.y * 128, n0 = blockIdx.x * 128;
    const int wm = (w >> 1) * 64, wn = (w & 1) * 64;
    const int lm = l & 15, kq = l >> 4;
    const int srow  = w * 32 + (l >> 2);      // + i*16
    const int scol  = (l & 3) * 16;
    const int sbyte = w * 2048 + l * 16;      // + i*1024

    intx4 acc[4][4] = {};

    for (int k0 = 0; k0 < HV_D; k0 += 64) {
        __syncthreads();
#pragma unroll
        for (int i = 0; i < 2; ++i) {
            const int r = srow + i * 16;
            const int lo = sbyte + i * 1024;
            GLD16(hvb + (size_t)(m0 + r) * HV_D + k0 + scol, (char*)sA + lo);
            GLD16(cT  + (size_t)(n0 + r) * HV_D + k0 + scol, (char*)sB + lo);
        }
        __syncthreads();
        intx4 b[4];
#pragma unroll
        for (int ns = 0; ns < 4; ++ns)
            b[ns] = *(const intx4*)&sB[(wn + ns * 16 + lm) * 64 + kq * 16];
#pragma unroll
        for (int ms = 0; ms < 4; ++ms) {
            intx4 a = *(const intx4*)&sA[(wm + ms * 16 + lm) * 64 + kq * 16];
#pragma unroll
            for (int ns = 0; ns < 4; ++ns)
                acc[ms][ns] = __builtin_amdgcn_mfma_i32_16x16x64_i8(a, b[ns], acc[ms][ns], 0, 0, 0);
        }
    }

#pragma unroll
    for (int ms = 0; ms < 4; ++ms) {
#pragma unroll
        for (int ns = 0; ns < 4; ++ns) {
            const int m = m0 + wm + ms * 16 + kq * 4;
            const int n = n0 + wn + ns * 16 + lm;
            if (n < NC) {
#pragma unroll
                for (int r = 0; r < 4; ++r)
                    scores[(size_t)(m + r) * NC + n] = (float)acc[ms][ns][r];
            }
        }
    }
}

extern "C" void kernel_launch(void* const* d_in, const int* in_sizes, int n_in,
                              void* d_out, int out_size, void* d_ws, size_t ws_size,
                              hipStream_t stream) {
    const float* x    = (const float*)d_in[0];   // [16384][2048]
    const float* proj = (const float*)d_in[1];   // [2048][8192]
    const float* chv  = (const float*)d_in[2];   // [8192][1000]
    float* out    = (float*)d_out;
    float* scores = out;                          // [16384][1000]
    float* hv_out = out + (size_t)SCORES_N;       // [16384][8192]

    // workspace layout (total 310,378,496 B)
    char* ws = (char*)d_ws;
    _Float16*    xh  = (_Float16*)(ws);                         //  64 MiB
    _Float16*    xl  = (_Float16*)(ws + (size_t)67108864);      //  64 MiB
    _Float16*    pT  = (_Float16*)(ws + (size_t)134217728);     //  32 MiB
    signed char* cT  = (signed char*)(ws + (size_t)167772160);  //   8 MiB
    signed char* hvb = (signed char*)(ws + (size_t)176160768);  // 128 MiB

    k_split<<<(B_DIM * IN_D / 4) / 256, 256, 0, stream>>>(x, xh, xl);
    k_transpose_proj<<<dim3(HV_D / 64, IN_D / 64), 256, 0, stream>>>(proj, pT);
    k_pack_class<<<(NCP * HV_D / 4) / 256, 256, 0, stream>>>(chv, cT);
    k_gemm1<<<dim3(HV_D / 128, B_DIM / 128), 256, 0, stream>>>(xh, xl, pT, hv_out, hvb);
    k_gemm2<<<dim3(NCP / 128, B_DIM / 128), 256, 0, stream>>>(hvb, cT, scores);
}

// Round 2
// 1726.755 us; speedup vs baseline: 1.1021x; 1.1021x over previous
//
#include <hip/hip_runtime.h>
#include <hip/hip_bf16.h>

typedef _Float16 half8  __attribute__((ext_vector_type(8)));
typedef _Float16 half4_t __attribute__((ext_vector_type(4)));
typedef float    floatx4 __attribute__((ext_vector_type(4)));
typedef int      intx4   __attribute__((ext_vector_type(4)));

#define B_DIM   16384
#define IN_D    2048
#define HV_D    8192
#define NC      1000
#define NCP     1024
#define SCORES_N (B_DIM * NC)

// async global->LDS, 16B per lane; LDS side is wave-uniform base + lane*16
#define GLD16(gp, lp) __builtin_amdgcn_global_load_lds( \
    (const __attribute__((address_space(1))) void*)(gp), \
    (__attribute__((address_space(3))) void*)(lp), 16, 0, 0)

// ---------- P1: Dekker split x (fp32) -> x_hi + x_lo (fp16), exact vs fp32 ----------
__global__ void k_split(const float* __restrict__ x, _Float16* __restrict__ xh,
                        _Float16* __restrict__ xl) {
    size_t i = (size_t)blockIdx.x * 256 + threadIdx.x;   // one float4 per thread
    floatx4 v = ((const floatx4*)x)[i];
    half4_t h, l;
#pragma unroll
    for (int j = 0; j < 4; ++j) {
        _Float16 hh = (_Float16)v[j];
        h[j] = hh;
        l[j] = (_Float16)(v[j] - (float)hh);
    }
    ((half4_t*)xh)[i] = h;
    ((half4_t*)xl)[i] = l;
}

// ---------- P2: proj [K=2048][N=8192] fp32 -> projT [N][K] fp16 (LDS-tiled) ----------
__global__ void k_transpose_proj(const float* __restrict__ p, _Float16* __restrict__ pT) {
    __shared__ float tile[64][65];
    const int t = threadIdx.x;
    const int nt = blockIdx.x * 64;
    const int kt = blockIdx.y * 64;
    const int tr = t >> 4, tc = (t & 15) * 4;
#pragma unroll
    for (int s = 0; s < 4; ++s) {
        int r = tr + s * 16;
        floatx4 v = *(const floatx4*)&p[(size_t)(kt + r) * HV_D + nt + tc];
        tile[r][tc] = v[0]; tile[r][tc + 1] = v[1];
        tile[r][tc + 2] = v[2]; tile[r][tc + 3] = v[3];
    }
    __syncthreads();
#pragma unroll
    for (int s = 0; s < 4; ++s) {
        int rn = tr + s * 16;
        half4_t o;
#pragma unroll
        for (int j = 0; j < 4; ++j) o[j] = (_Float16)tile[tc + j][rn];
        *(half4_t*)&pT[(size_t)(nt + rn) * IN_D + kt + tc] = o;
    }
}

// ---------- P3: class_hv [K=8192][1000] fp32 -> classT [1024][8192] i8, zero-padded ----------
__global__ void k_pack_class(const float* __restrict__ c, signed char* __restrict__ cT) {
    int tid = blockIdx.x * 256 + threadIdx.x;
    int idx = tid * 4;
    int n = idx >> 13;
    int k = idx & (HV_D - 1);
    int w = 0;
    if (n < NC) {
#pragma unroll
        for (int j = 0; j < 4; ++j) {
            float v = c[(size_t)(k + j) * NC + n];
            int b = (v >= 0.f) ? 1 : -1;
            w |= (b & 0xff) << (8 * j);
        }
    }
    *(int*)&cT[(size_t)n * HV_D + k] = w;
}

// ---------- G1: hv = x@proj via fp16 hi/lo split, binarize, write fp32 + i8 ----------
// 128x128 tile, BK=64, 4 waves (2x2), each wave 64x64 as 4x4 of 16x16x32 f16 MFMA.
// LDS tiles XOR-swizzled: row r's 16B chunk c stored at slot (c ^ (r&7)).
// global_load_lds forces slot = lane*16, so the LANE picks the swizzled global chunk;
// reads then hit 8 distinct 4-bank groups per quarter-wave (2-way = free, m136).
__launch_bounds__(256, 2)
__global__ void k_gemm1(const _Float16* __restrict__ xh, const _Float16* __restrict__ xl,
                        const _Float16* __restrict__ pT,
                        float* __restrict__ hv_out, signed char* __restrict__ hvb) {
    __shared__ _Float16 sAh[128 * 64];
    __shared__ _Float16 sAl[128 * 64];
    __shared__ _Float16 sB [128 * 64];
    const int t = threadIdx.x;
    const int w = t >> 6, l = t & 63;
    const int m0 = blockIdx.y * 128, n0 = blockIdx.x * 128;
    const int wm = (w >> 1) * 64, wn = (w & 1) * 64;
    const int lm = l & 15, kq = l >> 4;
    const int srow  = w * 32 + (l >> 3);                 // + i*8; (row & 7) == (l>>3)&7
    const int scol  = (((l & 7) ^ ((l >> 3) & 7))) * 8;  // swizzled source chunk (f16 units)
    const int sbyte = w * 4096 + l * 16;                 // + i*1024

    floatx4 acc[4][4] = {};

    for (int k0 = 0; k0 < IN_D; k0 += 64) {
        __syncthreads();
#pragma unroll
        for (int i = 0; i < 4; ++i) {
            const int r = srow + i * 8;
            const size_t ga = (size_t)(m0 + r) * IN_D + k0 + scol;
            const size_t gb = (size_t)(n0 + r) * IN_D + k0 + scol;
            const int lo = sbyte + i * 1024;
            GLD16(xh + ga, (char*)sAh + lo);
            GLD16(xl + ga, (char*)sAl + lo);
            GLD16(pT + gb, (char*)sB  + lo);
        }
        __syncthreads();
#pragma unroll
        for (int ks = 0; ks < 2; ++ks) {
            // fragment rows all have (row & 7) == (lm & 7); chunk = ks*4+kq
            const int csw = ((ks * 4 + kq) ^ (lm & 7)) * 8;   // swizzled slot (f16 units)
            half8 b[4];
#pragma unroll
            for (int ns = 0; ns < 4; ++ns)
                b[ns] = *(const half8*)&sB[(wn + ns * 16 + lm) * 64 + csw];
#pragma unroll
            for (int ms = 0; ms < 4; ++ms) {
                half8 a = *(const half8*)&sAh[(wm + ms * 16 + lm) * 64 + csw];
#pragma unroll
                for (int ns = 0; ns < 4; ++ns)
                    acc[ms][ns] = __builtin_amdgcn_mfma_f32_16x16x32_f16(a, b[ns], acc[ms][ns], 0, 0, 0);
            }
#pragma unroll
            for (int ms = 0; ms < 4; ++ms) {
                half8 a = *(const half8*)&sAl[(wm + ms * 16 + lm) * 64 + csw];
#pragma unroll
                for (int ns = 0; ns < 4; ++ns)
                    acc[ms][ns] = __builtin_amdgcn_mfma_f32_16x16x32_f16(a, b[ns], acc[ms][ns], 0, 0, 0);
            }
        }
    }

    // epilogue: C/D layout col=lane&15, row=(lane>>4)*4+reg
#pragma unroll
    for (int ms = 0; ms < 4; ++ms) {
#pragma unroll
        for (int ns = 0; ns < 4; ++ns) {
            const int m = m0 + wm + ms * 16 + kq * 4;
            const int n = n0 + wn + ns * 16 + lm;
#pragma unroll
            for (int r = 0; r < 4; ++r) {
                const int pos = (acc[ms][ns][r] >= 0.f);
                const size_t o = (size_t)(m + r) * HV_D + n;
                hv_out[o] = pos ? 1.f : -1.f;
                hvb[o] = (signed char)(pos ? 1 : -1);
            }
        }
    }
}

// ---------- G2: scores = hv_bin @ class_hv, exact in i8 (K=8192) ----------
// 128x128 tile, BK=128 (128B rows -> same XOR-8 swizzle), 64 k-iters,
// 32 i8 MFMA (16x16x64) per wave per iter.
__launch_bounds__(256, 2)
__global__ void k_gemm2(const signed char* __restrict__ hvb, const signed char* __restrict__ cT,
                        float* __restrict__ scores) {
    __shared__ signed char sA[128 * 128];
    __shared__ signed char sB[128 * 128];
    const int t = threadIdx.x;
    const int w = t >> 6, l = t & 63;
    const int m0 = blockIdx.y * 128, n0 = blockIdx.x * 128;
    const int wm = (w >> 1) * 64, wn = (w & 1) * 64;
    const int lm = l & 15, kq = l >> 4;
    const int srow  = w * 32 + (l >> 3);                  // + i*8
    const int scol  = (((l & 7) ^ ((l >> 3) & 7))) * 16;  // swizzled source chunk (bytes)
    const int sbyte = w * 4096 + l * 16;                  // + i*1024

    intx4 acc[4][4] = {};

    for (int k0 = 0; k0 < HV_D; k0 += 128) {
        __syncthreads();
#pragma unroll
        for (int i = 0; i < 4; ++i) {
            const int r = srow + i * 8;
            const int lo = sbyte + i * 1024;
            GLD16(hvb + (size_t)(m0 + r) * HV_D + k0 + scol, (char*)sA + lo);
            GLD16(cT  + (size_t)(n0 + r) * HV_D + k0 + scol, (char*)sB + lo);
        }
        __syncthreads();
#pragma unroll
        for (int ks = 0; ks < 2; ++ks) {
            const int csw = ((ks * 4 + kq) ^ (lm & 7)) * 16;  // bytes
            intx4 b[4];
#pragma unroll
            for (int ns = 0; ns < 4; ++ns)
                b[ns] = *(const intx4*)&sB[(wn + ns * 16 + lm) * 128 + csw];
#pragma unroll
            for (int ms = 0; ms < 4; ++ms) {
                intx4 a = *(const intx4*)&sA[(wm + ms * 16 + lm) * 128 + csw];
#pragma unroll
                for (int ns = 0; ns < 4; ++ns)
                    acc[ms][ns] = __builtin_amdgcn_mfma_i32_16x16x64_i8(a, b[ns], acc[ms][ns], 0, 0, 0);
            }
        }
    }

#pragma unroll
    for (int ms = 0; ms < 4; ++ms) {
#pragma unroll
        for (int ns = 0; ns < 4; ++ns) {
            const int m = m0 + wm + ms * 16 + kq * 4;
            const int n = n0 + wn + ns * 16 + lm;
            if (n < NC) {
#pragma unroll
                for (int r = 0; r < 4; ++r)
                    scores[(size_t)(m + r) * NC + n] = (float)acc[ms][ns][r];
            }
        }
    }
}

extern "C" void kernel_launch(void* const* d_in, const int* in_sizes, int n_in,
                              void* d_out, int out_size, void* d_ws, size_t ws_size,
                              hipStream_t stream) {
    const float* x    = (const float*)d_in[0];   // [16384][2048]
    const float* proj = (const float*)d_in[1];   // [2048][8192]
    const float* chv  = (const float*)d_in[2];   // [8192][1000]
    float* out    = (float*)d_out;
    float* scores = out;                          // [16384][1000]
    float* hv_out = out + (size_t)SCORES_N;       // [16384][8192]

    // workspace layout (total 310,378,496 B)
    char* ws = (char*)d_ws;
    _Float16*    xh  = (_Float16*)(ws);                         //  64 MiB
    _Float16*    xl  = (_Float16*)(ws + (size_t)67108864);      //  64 MiB
    _Float16*    pT  = (_Float16*)(ws + (size_t)134217728);     //  32 MiB
    signed char* cT  = (signed char*)(ws + (size_t)167772160);  //   8 MiB
    signed char* hvb = (signed char*)(ws + (size_t)176160768);  // 128 MiB

    k_split<<<(B_DIM * IN_D / 4) / 256, 256, 0, stream>>>(x, xh, xl);
    k_transpose_proj<<<dim3(HV_D / 64, IN_D / 64), 256, 0, stream>>>(proj, pT);
    k_pack_class<<<(NCP * HV_D / 4) / 256, 256, 0, stream>>>(chv, cT);
    k_gemm1<<<dim3(HV_D / 128, B_DIM / 128), 256, 0, stream>>>(xh, xl, pT, hv_out, hvb);
    k_gemm2<<<dim3(NCP / 128, B_DIM / 128), 256, 0, stream>>>(hvb, cT, scores);
}

// Round 3
// 1629.613 us; speedup vs baseline: 1.1678x; 1.0596x over previous
//
#include <hip/hip_runtime.h>
#include <hip/hip_bf16.h>

typedef _Float16 half8  __attribute__((ext_vector_type(8)));
typedef _Float16 half4_t __attribute__((ext_vector_type(4)));
typedef float    floatx4 __attribute__((ext_vector_type(4)));
typedef int      intx4   __attribute__((ext_vector_type(4)));

#define B_DIM   16384
#define IN_D    2048
#define HV_D    8192
#define NC      1000
#define NCP     1024
#define SCORES_N (B_DIM * NC)

// async global->LDS, 16B per lane; LDS side is wave-uniform base + lane*16
#define GLD16(gp, lp) __builtin_amdgcn_global_load_lds( \
    (const __attribute__((address_space(1))) void*)(gp), \
    (__attribute__((address_space(3))) void*)(lp), 16, 0, 0)

// ---------- P1: Dekker split x (fp32) -> x_hi + x_lo (fp16), exact vs fp32 ----------
__global__ void k_split(const float* __restrict__ x, _Float16* __restrict__ xh,
                        _Float16* __restrict__ xl) {
    size_t i = (size_t)blockIdx.x * 256 + threadIdx.x;
    floatx4 v = ((const floatx4*)x)[i];
    half4_t h, l;
#pragma unroll
    for (int j = 0; j < 4; ++j) {
        _Float16 hh = (_Float16)v[j];
        h[j] = hh;
        l[j] = (_Float16)(v[j] - (float)hh);
    }
    ((half4_t*)xh)[i] = h;
    ((half4_t*)xl)[i] = l;
}

// ---------- P2: proj [K=2048][N=8192] fp32 -> projT [N][K] fp16 (LDS-tiled) ----------
__global__ void k_transpose_proj(const float* __restrict__ p, _Float16* __restrict__ pT) {
    __shared__ float tile[64][65];
    const int t = threadIdx.x;
    const int nt = blockIdx.x * 64;
    const int kt = blockIdx.y * 64;
    const int tr = t >> 4, tc = (t & 15) * 4;
#pragma unroll
    for (int s = 0; s < 4; ++s) {
        int r = tr + s * 16;
        floatx4 v = *(const floatx4*)&p[(size_t)(kt + r) * HV_D + nt + tc];
        tile[r][tc] = v[0]; tile[r][tc + 1] = v[1];
        tile[r][tc + 2] = v[2]; tile[r][tc + 3] = v[3];
    }
    __syncthreads();
#pragma unroll
    for (int s = 0; s < 4; ++s) {
        int rn = tr + s * 16;
        half4_t o;
#pragma unroll
        for (int j = 0; j < 4; ++j) o[j] = (_Float16)tile[tc + j][rn];
        *(half4_t*)&pT[(size_t)(nt + rn) * IN_D + kt + tc] = o;
    }
}

// ---------- P3: class_hv [K=8192][1000] fp32 -> classT [1024][8192] i8, zero-padded ----------
__global__ void k_pack_class(const float* __restrict__ c, signed char* __restrict__ cT) {
    int tid = blockIdx.x * 256 + threadIdx.x;
    int idx = tid * 4;
    int n = idx >> 13;
    int k = idx & (HV_D - 1);
    int w = 0;
    if (n < NC) {
#pragma unroll
        for (int j = 0; j < 4; ++j) {
            float v = c[(size_t)(k + j) * NC + n];
            int b = (v >= 0.f) ? 1 : -1;
            w |= (b & 0xff) << (8 * j);
        }
    }
    *(int*)&cT[(size_t)n * HV_D + k] = w;
}

// ---------- G1: hv = x@proj via fp16 hi/lo split, binarize, write fp32 + i8 ----------
// 128(M)x256(N) block tile, BK=64, 4 waves as 2x2, wave tile 64x128 (4x8 of 16x16x32).
// LDS row-major with XOR-8 16B-chunk swizzle: tile row r, chunk c at r*64 + (c^(r&7))*8 (f16).
// Staging (global_load_lds, slot=lane*16): round i writes rows i*32+w*8+(l>>3), so the lane
// FETCHES the swizzled global chunk; reads are then 2-way-per-bank (free, m136).
__launch_bounds__(256, 2)
__global__ void k_gemm1(const _Float16* __restrict__ xh, const _Float16* __restrict__ xl,
                        const _Float16* __restrict__ pT,
                        float* __restrict__ hv_out, signed char* __restrict__ hvb) {
    __shared__ _Float16 sAh[128 * 64];   // 16 KB
    __shared__ _Float16 sAl[128 * 64];   // 16 KB
    __shared__ _Float16 sB [256 * 64];   // 32 KB
    const int t = threadIdx.x;
    const int w = t >> 6, l = t & 63;
    const int m0 = blockIdx.y * 128, n0 = blockIdx.x * 256;
    const int wm = (w >> 1) * 64, wn = (w & 1) * 128;
    const int lm = l & 15, kq = l >> 4;
    const int srow  = w * 8 + (l >> 3);                  // + i*32
    const int scol  = (((l & 7) ^ ((l >> 3) & 7))) * 8;  // swizzled source chunk (f16 units)
    const int sbyte = w * 1024 + l * 16;                 // + i*4096

    floatx4 acc[4][8] = {};

    for (int k0 = 0; k0 < IN_D; k0 += 64) {
        __syncthreads();
#pragma unroll
        for (int i = 0; i < 4; ++i) {
            const size_t ga = (size_t)(m0 + srow + i * 32) * IN_D + k0 + scol;
            const int lo = sbyte + i * 4096;
            GLD16(xh + ga, (char*)sAh + lo);
            GLD16(xl + ga, (char*)sAl + lo);
        }
#pragma unroll
        for (int i = 0; i < 8; ++i) {
            const size_t gb = (size_t)(n0 + srow + i * 32) * IN_D + k0 + scol;
            GLD16(pT + gb, (char*)sB + sbyte + i * 4096);
        }
        __syncthreads();
#pragma unroll
        for (int ks = 0; ks < 2; ++ks) {
            const int csw = ((ks * 4 + kq) ^ (lm & 7)) * 8;   // swizzled slot (f16 units)
            half8 b[8];
#pragma unroll
            for (int ns = 0; ns < 8; ++ns)
                b[ns] = *(const half8*)&sB[(wn + ns * 16 + lm) * 64 + csw];
#pragma unroll
            for (int ms = 0; ms < 4; ++ms) {
                half8 a = *(const half8*)&sAh[(wm + ms * 16 + lm) * 64 + csw];
#pragma unroll
                for (int ns = 0; ns < 8; ++ns)
                    acc[ms][ns] = __builtin_amdgcn_mfma_f32_16x16x32_f16(a, b[ns], acc[ms][ns], 0, 0, 0);
            }
#pragma unroll
            for (int ms = 0; ms < 4; ++ms) {
                half8 a = *(const half8*)&sAl[(wm + ms * 16 + lm) * 64 + csw];
#pragma unroll
                for (int ns = 0; ns < 8; ++ns)
                    acc[ms][ns] = __builtin_amdgcn_mfma_f32_16x16x32_f16(a, b[ns], acc[ms][ns], 0, 0, 0);
            }
        }
    }

    // epilogue: C/D layout col=lane&15, row=(lane>>4)*4+reg
#pragma unroll
    for (int ms = 0; ms < 4; ++ms) {
#pragma unroll
        for (int ns = 0; ns < 8; ++ns) {
            const int m = m0 + wm + ms * 16 + kq * 4;
            const int n = n0 + wn + ns * 16 + lm;
#pragma unroll
            for (int r = 0; r < 4; ++r) {
                const int pos = (acc[ms][ns][r] >= 0.f);
                const size_t o = (size_t)(m + r) * HV_D + n;
                hv_out[o] = pos ? 1.f : -1.f;
                hvb[o] = (signed char)(pos ? 1 : -1);
            }
        }
    }
}

// ---------- G2: scores = hv_bin @ class_hv, exact in i8 (K=8192) ----------
// 128(M)x256(N) block tile, BK=128, wave tile 64x128 (4x8 of 16x16x64 i8), 64 k-iters.
__launch_bounds__(256, 2)
__global__ void k_gemm2(const signed char* __restrict__ hvb, const signed char* __restrict__ cT,
                        float* __restrict__ scores) {
    __shared__ signed char sA[128 * 128];   // 16 KB
    __shared__ signed char sB[256 * 128];   // 32 KB
    const int t = threadIdx.x;
    const int w = t >> 6, l = t & 63;
    const int m0 = blockIdx.y * 128, n0 = blockIdx.x * 256;
    const int wm = (w >> 1) * 64, wn = (w & 1) * 128;
    const int lm = l & 15, kq = l >> 4;
    const int srow  = w * 8 + (l >> 3);                   // + i*32
    const int scol  = (((l & 7) ^ ((l >> 3) & 7))) * 16;  // swizzled source chunk (bytes)
    const int sbyte = w * 1024 + l * 16;                  // + i*4096

    intx4 acc[4][8] = {};

    for (int k0 = 0; k0 < HV_D; k0 += 128) {
        __syncthreads();
#pragma unroll
        for (int i = 0; i < 4; ++i)
            GLD16(hvb + (size_t)(m0 + srow + i * 32) * HV_D + k0 + scol,
                  (char*)sA + sbyte + i * 4096);
#pragma unroll
        for (int i = 0; i < 8; ++i)
            GLD16(cT + (size_t)(n0 + srow + i * 32) * HV_D + k0 + scol,
                  (char*)sB + sbyte + i * 4096);
        __syncthreads();
#pragma unroll
        for (int ks = 0; ks < 2; ++ks) {
            const int csw = ((ks * 4 + kq) ^ (lm & 7)) * 16;  // bytes
            intx4 b[8];
#pragma unroll
            for (int ns = 0; ns < 8; ++ns)
                b[ns] = *(const intx4*)&sB[(wn + ns * 16 + lm) * 128 + csw];
#pragma unroll
            for (int ms = 0; ms < 4; ++ms) {
                intx4 a = *(const intx4*)&sA[(wm + ms * 16 + lm) * 128 + csw];
#pragma unroll
                for (int ns = 0; ns < 8; ++ns)
                    acc[ms][ns] = __builtin_amdgcn_mfma_i32_16x16x64_i8(a, b[ns], acc[ms][ns], 0, 0, 0);
            }
        }
    }

#pragma unroll
    for (int ms = 0; ms < 4; ++ms) {
#pragma unroll
        for (int ns = 0; ns < 8; ++ns) {
            const int m = m0 + wm + ms * 16 + kq * 4;
            const int n = n0 + wn + ns * 16 + lm;
            if (n < NC) {
#pragma unroll
                for (int r = 0; r < 4; ++r)
                    scores[(size_t)(m + r) * NC + n] = (float)acc[ms][ns][r];
            }
        }
    }
}

extern "C" void kernel_launch(void* const* d_in, const int* in_sizes, int n_in,
                              void* d_out, int out_size, void* d_ws, size_t ws_size,
                              hipStream_t stream) {
    const float* x    = (const float*)d_in[0];   // [16384][2048]
    const float* proj = (const float*)d_in[1];   // [2048][8192]
    const float* chv  = (const float*)d_in[2];   // [8192][1000]
    float* out    = (float*)d_out;
    float* scores = out;                          // [16384][1000]
    float* hv_out = out + (size_t)SCORES_N;       // [16384][8192]

    // workspace layout (total 310,378,496 B)
    char* ws = (char*)d_ws;
    _Float16*    xh  = (_Float16*)(ws);                         //  64 MiB
    _Float16*    xl  = (_Float16*)(ws + (size_t)67108864);      //  64 MiB
    _Float16*    pT  = (_Float16*)(ws + (size_t)134217728);     //  32 MiB
    signed char* cT  = (signed char*)(ws + (size_t)167772160);  //   8 MiB
    signed char* hvb = (signed char*)(ws + (size_t)176160768);  // 128 MiB

    k_split<<<(B_DIM * IN_D / 4) / 256, 256, 0, stream>>>(x, xh, xl);
    k_transpose_proj<<<dim3(HV_D / 64, IN_D / 64), 256, 0, stream>>>(proj, pT);
    k_pack_class<<<(NCP * HV_D / 4) / 256, 256, 0, stream>>>(chv, cT);
    k_gemm1<<<dim3(HV_D / 256, B_DIM / 128), 256, 0, stream>>>(xh, xl, pT, hv_out, hvb);
    k_gemm2<<<dim3(NCP / 256, B_DIM / 128), 256, 0, stream>>>(hvb, cT, scores);
}